// Round 1
// baseline (271.445 us; speedup 1.0000x reference)
//
#include <hip/hip_runtime.h>
#include <math.h>

#define NS    32768          // samples per sequence
#define NB    128            // interpolation bins
#define NSEQ  128            // 16 batches * 8 heads
#define SPLIT 4              // blocks per sequence
#define QN    (NS / SPLIT)   // 8192 samples per block
#define TPB   512
#define CH    (QN / TPB)     // 16 samples per thread (never crosses a segment)

__device__ __forceinline__ float fsin(double x) {
    // sin(x) via f64 range reduction to revolutions + v_sin_f32
    double u = x * 0.15915494309189533576888376337251;  // 1/(2*pi)
    double f = u - rint(u);                              // [-0.5, 0.5]
    return __builtin_amdgcn_sinf((float)f);              // sin(2*pi*f)
}

// segment params for a CH-aligned chunk starting at global sample ci0
__device__ __forceinline__ void seg_params(int ci0, int& lo, int& hi,
                                           double& w0, double& wst) {
    if (ci0 < 128)            { lo = 0;   hi = 1;   w0 = 0.0; wst = 0.0; }
    else if (ci0 >= NS - 128) { lo = 127; hi = 127; w0 = 0.0; wst = 0.0; }
    else {
        lo = (ci0 - 128) >> 8;  hi = lo + 1;
        int off = (ci0 - 128) & 255;
        w0 = (off + 0.5) * (1.0 / 256.0);
        wst = 1.0 / 256.0;
    }
}

__global__ __launch_bounds__(TPB)
void fm_kernel(const float* __restrict__ xg, const float* __restrict__ ng,
               float* __restrict__ out) {
    __shared__ double bins[6][NB];      // amp,f0,mix,std,modf,b
    __shared__ double lred[TPB / 64][3];
    __shared__ double lbase[TPB / 64][3];
    __shared__ double pref[3];

    const double PI_  = 3.14159265358979323846;
    const double MINF = 40.0 / 11025.0;
    const double FRNG = (4000.0 - 40.0) / 11025.0;
    const double SUMJ = (CH * (CH - 1) / 2) * (1.0 / 256.0);  // sum of j*step

    int bx   = blockIdx.x;
    int s    = bx >> 2;        // sequence = b*8 + h
    int p    = bx & (SPLIT - 1);
    int tid  = threadIdx.x;
    int lane = tid & 63;
    int wid  = tid >> 6;

    // ---- per-bin values in f64 (redundant across the 4 quarter-blocks, cheap)
    const float* xs = xg + s * 10 * 128;
    for (int idx = tid; idx < 6 * NB; idx += TPB) {
        int q = idx >> 7, j = idx & 127;
        double v;
        if (q == 0) {
            double a0 = (double)xs[j], a1 = (double)xs[128 + j];
            v = sqrt(a0 * a0 + a1 * a1);
        } else {
            int c = (q - 1) * 2;
            double yy = (double)xs[(c + 1) * 128 + j];
            double xx = (double)xs[c * 128 + j];
            double ang = atan2(yy, xx) / PI_;
            double sh, sc;
            if      (q == 1) { sh = MINF; sc = FRNG; }   // f0
            else if (q == 2) { sh = 1.0;  sc = 0.5;  }   // mix
            else if (q == 3) { sh = MINF; sc = FRNG; }   // noise_std
            else if (q == 4) { sh = 0.25; sc = 4.75; }   // mod_factor
            else             { sh = 0.1;  sc = 9.9;  }   // b
            v = sh + ang * sc;
        }
        bins[q][j] = v;
    }
    __syncthreads();

    const float* ns_ = ng + s * NS;

    // ---- redundant prefix over the p*QN preceding samples (3 stream totals)
    double p1 = 0.0, p3 = 0.0, p2 = 0.0;
    int npre = p * (QN / CH);
    for (int ch = tid; ch < npre; ch += TPB) {
        int ci0 = ch * CH;
        int lo, hi; double w0, wst;
        seg_params(ci0, lo, hi, w0, wst);
        double f0L = bins[1][lo], dF0 = bins[1][hi] - f0L;
        double stL = bins[3][lo], dSt = bins[3][hi] - stL;
        double mfL = bins[4][lo], dMf = bins[4][hi] - mfL;
        double sumw = (wst != 0.0) ? (CH * w0 + SUMJ) : 0.0;
        double t3 = CH * f0L + dF0 * sumw;
        p3 += t3;
        p2 += CH * mfL + dMf * sumw;
        const float4* nn4 = reinterpret_cast<const float4*>(ns_ + ci0);
        double w = w0, tn = 0.0;
        #pragma unroll
        for (int j4 = 0; j4 < CH / 4; ++j4) {
            float4 nv = nn4[j4];
            tn += (double)nv.x * (stL + w * dSt); w += wst;
            tn += (double)nv.y * (stL + w * dSt); w += wst;
            tn += (double)nv.z * (stL + w * dSt); w += wst;
            tn += (double)nv.w * (stL + w * dSt); w += wst;
        }
        p1 += t3 + tn;
    }
    #pragma unroll
    for (int d = 32; d; d >>= 1) {
        p1 += __shfl_down(p1, d);
        p3 += __shfl_down(p3, d);
        p2 += __shfl_down(p2, d);
    }
    if (lane == 0) { lred[wid][0] = p1; lred[wid][1] = p3; lred[wid][2] = p2; }
    __syncthreads();
    if (tid == 0) {
        double a = 0, b = 0, c = 0;
        for (int wv = 0; wv < TPB / 64; ++wv) {
            a += lred[wv][0]; b += lred[wv][1]; c += lred[wv][2];
        }
        pref[0] = a; pref[1] = b; pref[2] = c;
    }
    __syncthreads();

    // ---- this thread's chunk
    int i0 = p * QN + tid * CH;
    int lo, hi; double w0, wst;
    seg_params(i0, lo, hi, w0, wst);
    double f0L = bins[1][lo], dF0 = bins[1][hi] - f0L;
    double stL = bins[3][lo], dSt = bins[3][hi] - stL;
    double mfL = bins[4][lo], dMf = bins[4][hi] - mfL;
    double amL = bins[0][lo], dAm = bins[0][hi] - amL;
    double mxL = bins[2][lo], dMx = bins[2][hi] - mxL;
    double bL  = bins[5][lo], dB  = bins[5][hi] - bL;

    double sumw = (wst != 0.0) ? (CH * w0 + SUMJ) : 0.0;
    double T3 = CH * f0L + dF0 * sumw;
    double T2 = CH * mfL + dMf * sumw;
    double TN = 0.0;
    const float4* nn4 = reinterpret_cast<const float4*>(ns_ + i0);
    {
        double w = w0;
        #pragma unroll
        for (int j4 = 0; j4 < CH / 4; ++j4) {
            float4 nv = nn4[j4];
            TN += (double)nv.x * (stL + w * dSt); w += wst;
            TN += (double)nv.y * (stL + w * dSt); w += wst;
            TN += (double)nv.z * (stL + w * dSt); w += wst;
            TN += (double)nv.w * (stL + w * dSt); w += wst;
        }
    }
    double T1 = T3 + TN;

    // ---- block-wide inclusive scan of (T1,T3,T2)
    double v1 = T1, v3 = T3, v2 = T2;
    #pragma unroll
    for (int d = 1; d < 64; d <<= 1) {
        double u1 = __shfl_up(v1, d);
        double u3 = __shfl_up(v3, d);
        double u2 = __shfl_up(v2, d);
        if (lane >= d) { v1 += u1; v3 += u3; v2 += u2; }
    }
    if (lane == 63) { lred[wid][0] = v1; lred[wid][1] = v3; lred[wid][2] = v2; }
    __syncthreads();
    if (tid == 0) {
        double a = 0, b = 0, c = 0;
        for (int wv = 0; wv < TPB / 64; ++wv) {
            lbase[wv][0] = a; lbase[wv][1] = b; lbase[wv][2] = c;
            a += lred[wv][0]; b += lred[wv][1]; c += lred[wv][2];
        }
    }
    __syncthreads();

    double a1 = pref[0] + lbase[wid][0] + (v1 - T1);
    double a3 = pref[1] + lbase[wid][1] + (v3 - T3);
    double a2 = pref[2] + lbase[wid][2] + (v2 - T2);

    // ---- emit samples
    float* op = out + (s >> 3) * NS + i0;
    double w = w0;
    #pragma unroll
    for (int j4 = 0; j4 < CH / 4; ++j4) {
        float4 nv = nn4[j4];
        float nvv[4] = {nv.x, nv.y, nv.z, nv.w};
        #pragma unroll
        for (int k = 0; k < 4; ++k) {
            int j = j4 * 4 + k;
            double nd   = (double)nvv[k];
            double f0v  = f0L + w * dF0;
            double stv  = stL + w * dSt;
            double mfv  = mfL + w * dMf;
            a1 += f0v + nd * stv;   // cs1
            a3 += f0v;              // cs3
            a2 += mfv;              // cs2
            double ampv = amL + w * dAm;
            double mixv = mxL + w * dMx;
            double bv   = bL  + w * dB;
            double harm = ampv * mixv;
            double namp = ampv * (1.0 - mixv);
            float s1 = fsin(a1);
            float s2 = fsin(a2);
            double mod = bv * (double)s2;
            float s3 = fsin(a3 + mod);
            float mixed = (float)namp * s1 + (float)harm * s3;
            atomicAdd(op + j, 0.125f * mixed);
            w += wst;
        }
    }
}

extern "C" void kernel_launch(void* const* d_in, const int* in_sizes, int n_in,
                              void* d_out, int out_size, void* d_ws, size_t ws_size,
                              hipStream_t stream) {
    const float* x     = (const float*)d_in[0];
    const float* noise = (const float*)d_in[1];
    float* out = (float*)d_out;
    hipMemsetAsync(out, 0, (size_t)out_size * sizeof(float), stream);
    fm_kernel<<<NSEQ * SPLIT, TPB, 0, stream>>>(x, noise, out);
}

// Round 2
// 88.677 us; speedup vs baseline: 3.0611x; 3.0611x over previous
//
#include <hip/hip_runtime.h>
#include <math.h>

#define NS    32768          // samples per sequence
#define NB    128            // interpolation bins
#define NSEQ  128            // 16 batches * 8 heads
#define SPLIT 4              // blocks per sequence
#define QN    (NS / SPLIT)   // 8192 samples per block
#define TPB   512
#define CH    (QN / TPB)     // 16 samples per thread (never crosses a segment)

__device__ __forceinline__ float fsin(double x) {
    // sin(x) via f64 range reduction to revolutions + v_sin_f32
    double u = x * 0.15915494309189533576888376337251;  // 1/(2*pi)
    double f = u - rint(u);                              // [-0.5, 0.5]
    return __builtin_amdgcn_sinf((float)f);              // sin(2*pi*f)
}

// segment params for a CH-aligned chunk starting at global sample ci0
__device__ __forceinline__ void seg_params(int ci0, int& lo, int& hi,
                                           double& w0, double& wst) {
    if (ci0 < 128)            { lo = 0;   hi = 1;   w0 = 0.0; wst = 0.0; }
    else if (ci0 >= NS - 128) { lo = 127; hi = 127; w0 = 0.0; wst = 0.0; }
    else {
        lo = (ci0 - 128) >> 8;  hi = lo + 1;
        int off = (ci0 - 128) & 255;
        w0 = (off + 0.5) * (1.0 / 256.0);
        wst = 1.0 / 256.0;
    }
}

// use_atomic=0: write per-head signal to wsig (no scaling)
// use_atomic=1: fallback path (tiny ws), atomicAdd 0.125*mixed into wsig(=out)
template <int USE_ATOMIC>
__global__ __launch_bounds__(TPB)
void fm_kernel(const float* __restrict__ xg, const float* __restrict__ ng,
               float* __restrict__ wsig) {
    __shared__ double bins[6][NB];      // amp,f0,mix,std,modf,b
    __shared__ double lred[TPB / 64][3];
    __shared__ double lbase[TPB / 64][3];
    __shared__ double pref[3];

    const double PI_  = 3.14159265358979323846;
    const double MINF = 40.0 / 11025.0;
    const double FRNG = (4000.0 - 40.0) / 11025.0;
    const double SUMJ = (CH * (CH - 1) / 2) * (1.0 / 256.0);  // sum of j*step

    int bx   = blockIdx.x;
    int s    = bx >> 2;        // sequence = b*8 + h
    int p    = bx & (SPLIT - 1);
    int tid  = threadIdx.x;
    int lane = tid & 63;
    int wid  = tid >> 6;

    // ---- per-bin values in f64 (redundant across the 4 quarter-blocks, cheap)
    const float* xs = xg + s * 10 * 128;
    for (int idx = tid; idx < 6 * NB; idx += TPB) {
        int q = idx >> 7, j = idx & 127;
        double v;
        if (q == 0) {
            double a0 = (double)xs[j], a1 = (double)xs[128 + j];
            v = sqrt(a0 * a0 + a1 * a1);
        } else {
            int c = (q - 1) * 2;
            double yy = (double)xs[(c + 1) * 128 + j];
            double xx = (double)xs[c * 128 + j];
            double ang = atan2(yy, xx) / PI_;
            double sh, sc;
            if      (q == 1) { sh = MINF; sc = FRNG; }   // f0
            else if (q == 2) { sh = 1.0;  sc = 0.5;  }   // mix
            else if (q == 3) { sh = MINF; sc = FRNG; }   // noise_std
            else if (q == 4) { sh = 0.25; sc = 4.75; }   // mod_factor
            else             { sh = 0.1;  sc = 9.9;  }   // b
            v = sh + ang * sc;
        }
        bins[q][j] = v;
    }
    __syncthreads();

    const float* ns_ = ng + s * NS;

    // ---- redundant prefix over the p*QN preceding samples (3 stream totals)
    double p1 = 0.0, p3 = 0.0, p2 = 0.0;
    int npre = p * (QN / CH);
    for (int ch = tid; ch < npre; ch += TPB) {
        int ci0 = ch * CH;
        int lo, hi; double w0, wst;
        seg_params(ci0, lo, hi, w0, wst);
        double f0L = bins[1][lo], dF0 = bins[1][hi] - f0L;
        double stL = bins[3][lo], dSt = bins[3][hi] - stL;
        double mfL = bins[4][lo], dMf = bins[4][hi] - mfL;
        double sumw = (wst != 0.0) ? (CH * w0 + SUMJ) : 0.0;
        double t3 = CH * f0L + dF0 * sumw;
        p3 += t3;
        p2 += CH * mfL + dMf * sumw;
        const float4* nn4 = reinterpret_cast<const float4*>(ns_ + ci0);
        double w = w0, tn = 0.0;
        #pragma unroll
        for (int j4 = 0; j4 < CH / 4; ++j4) {
            float4 nv = nn4[j4];
            tn += (double)nv.x * (stL + w * dSt); w += wst;
            tn += (double)nv.y * (stL + w * dSt); w += wst;
            tn += (double)nv.z * (stL + w * dSt); w += wst;
            tn += (double)nv.w * (stL + w * dSt); w += wst;
        }
        p1 += t3 + tn;
    }
    #pragma unroll
    for (int d = 32; d; d >>= 1) {
        p1 += __shfl_down(p1, d);
        p3 += __shfl_down(p3, d);
        p2 += __shfl_down(p2, d);
    }
    if (lane == 0) { lred[wid][0] = p1; lred[wid][1] = p3; lred[wid][2] = p2; }
    __syncthreads();
    if (tid == 0) {
        double a = 0, b = 0, c = 0;
        for (int wv = 0; wv < TPB / 64; ++wv) {
            a += lred[wv][0]; b += lred[wv][1]; c += lred[wv][2];
        }
        pref[0] = a; pref[1] = b; pref[2] = c;
    }
    __syncthreads();

    // ---- this thread's chunk
    int i0 = p * QN + tid * CH;
    int lo, hi; double w0, wst;
    seg_params(i0, lo, hi, w0, wst);
    double f0L = bins[1][lo], dF0 = bins[1][hi] - f0L;
    double stL = bins[3][lo], dSt = bins[3][hi] - stL;
    double mfL = bins[4][lo], dMf = bins[4][hi] - mfL;
    double amL = bins[0][lo], dAm = bins[0][hi] - amL;
    double mxL = bins[2][lo], dMx = bins[2][hi] - mxL;
    double bL  = bins[5][lo], dB  = bins[5][hi] - bL;

    double sumw = (wst != 0.0) ? (CH * w0 + SUMJ) : 0.0;
    double T3 = CH * f0L + dF0 * sumw;
    double T2 = CH * mfL + dMf * sumw;
    double TN = 0.0;
    const float4* nn4 = reinterpret_cast<const float4*>(ns_ + i0);
    {
        double w = w0;
        #pragma unroll
        for (int j4 = 0; j4 < CH / 4; ++j4) {
            float4 nv = nn4[j4];
            TN += (double)nv.x * (stL + w * dSt); w += wst;
            TN += (double)nv.y * (stL + w * dSt); w += wst;
            TN += (double)nv.z * (stL + w * dSt); w += wst;
            TN += (double)nv.w * (stL + w * dSt); w += wst;
        }
    }
    double T1 = T3 + TN;

    // ---- block-wide inclusive scan of (T1,T3,T2)
    double v1 = T1, v3 = T3, v2 = T2;
    #pragma unroll
    for (int d = 1; d < 64; d <<= 1) {
        double u1 = __shfl_up(v1, d);
        double u3 = __shfl_up(v3, d);
        double u2 = __shfl_up(v2, d);
        if (lane >= d) { v1 += u1; v3 += u3; v2 += u2; }
    }
    if (lane == 63) { lred[wid][0] = v1; lred[wid][1] = v3; lred[wid][2] = v2; }
    __syncthreads();
    if (tid == 0) {
        double a = 0, b = 0, c = 0;
        for (int wv = 0; wv < TPB / 64; ++wv) {
            lbase[wv][0] = a; lbase[wv][1] = b; lbase[wv][2] = c;
            a += lred[wv][0]; b += lred[wv][1]; c += lred[wv][2];
        }
    }
    __syncthreads();

    double a1 = pref[0] + lbase[wid][0] + (v1 - T1);
    double a3 = pref[1] + lbase[wid][1] + (v3 - T3);
    double a2 = pref[2] + lbase[wid][2] + (v2 - T2);

    // ---- emit samples (register-buffered, then full float4 stores — no atomics)
    float arr[CH];
    double w = w0;
    #pragma unroll
    for (int j4 = 0; j4 < CH / 4; ++j4) {
        float4 nv = nn4[j4];
        float nvv[4] = {nv.x, nv.y, nv.z, nv.w};
        #pragma unroll
        for (int k = 0; k < 4; ++k) {
            int j = j4 * 4 + k;
            double nd   = (double)nvv[k];
            double f0v  = f0L + w * dF0;
            double stv  = stL + w * dSt;
            double mfv  = mfL + w * dMf;
            a1 += f0v + nd * stv;   // cs1
            a3 += f0v;              // cs3
            a2 += mfv;              // cs2
            double ampv = amL + w * dAm;
            double mixv = mxL + w * dMx;
            double bv   = bL  + w * dB;
            double harm = ampv * mixv;
            double namp = ampv * (1.0 - mixv);
            float s1 = fsin(a1);
            float s2 = fsin(a2);
            double mod = bv * (double)s2;
            float s3 = fsin(a3 + mod);
            arr[j] = (float)namp * s1 + (float)harm * s3;
            w += wst;
        }
    }
    if (USE_ATOMIC) {
        float* op = wsig + (s >> 3) * NS + i0;
        #pragma unroll
        for (int j = 0; j < CH; ++j) atomicAdd(op + j, 0.125f * arr[j]);
    } else {
        float4* wp = reinterpret_cast<float4*>(wsig + s * NS + i0);
        #pragma unroll
        for (int j4 = 0; j4 < CH / 4; ++j4) {
            wp[j4] = make_float4(arr[j4 * 4 + 0], arr[j4 * 4 + 1],
                                 arr[j4 * 4 + 2], arr[j4 * 4 + 3]);
        }
    }
}

// reduce 8 heads -> mean: out[b, i] = 0.125 * sum_h wsig[(b*8+h)*NS + i]
__global__ __launch_bounds__(256)
void head_reduce_kernel(const float* __restrict__ wsig, float* __restrict__ out) {
    int t  = blockIdx.x * 256 + threadIdx.x;      // float4 index, [0, 16*NS/4)
    int i4 = t & (NS / 4 - 1);
    int b  = t >> 13;                              // t / (NS/4)
    const float4* wp = reinterpret_cast<const float4*>(wsig) + (size_t)b * 8 * (NS / 4) + i4;
    float4 acc = wp[0];
    #pragma unroll
    for (int h = 1; h < 8; ++h) {
        float4 v = wp[(size_t)h * (NS / 4)];
        acc.x += v.x; acc.y += v.y; acc.z += v.z; acc.w += v.w;
    }
    acc.x *= 0.125f; acc.y *= 0.125f; acc.z *= 0.125f; acc.w *= 0.125f;
    reinterpret_cast<float4*>(out)[t] = acc;
}

extern "C" void kernel_launch(void* const* d_in, const int* in_sizes, int n_in,
                              void* d_out, int out_size, void* d_ws, size_t ws_size,
                              hipStream_t stream) {
    const float* x     = (const float*)d_in[0];
    const float* noise = (const float*)d_in[1];
    float* out = (float*)d_out;
    const size_t need = (size_t)NSEQ * NS * sizeof(float);  // 16 MB
    if (ws_size >= need) {
        float* wsig = (float*)d_ws;
        fm_kernel<0><<<NSEQ * SPLIT, TPB, 0, stream>>>(x, noise, wsig);
        head_reduce_kernel<<<16 * NS / 4 / 256, 256, 0, stream>>>(wsig, out);
    } else {
        // fallback: atomic accumulation directly into out
        hipMemsetAsync(out, 0, (size_t)out_size * sizeof(float), stream);
        fm_kernel<1><<<NSEQ * SPLIT, TPB, 0, stream>>>(x, noise, out);
    }
}